// Round 9
// baseline (239.464 us; speedup 1.0000x reference)
//
#include <hip/hip_runtime.h>
#include <hip/hip_bf16.h>
#include <hip/hip_fp16.h>

// ---------------------------------------------------------------------------
// MSDeformableAttention on MI355X — round 8 (= audited round 7; r7 bench was
// an infra failure, same mode as round 1 which later ran clean)
//  - m97-geometry split-f16 MFMA GEMM: 128x128 tile, 4 waves, 4x4 frags/wave
//    (32 FLOP/LDS-byte), BK=32, global_load_lds staging, XOR-swizzled LDS.
//  - value+off+attn GEMMs fused into one dispatch; off written to d_out
//    (scratch reuse; final GEMM overwrites all of d_out).
//  - sampler v4: 4 queries/block, 4 channels/thread (8B gathers), f32x4 FMA.
// Split trick: C = Ahi*Bhi + Alo*Bhi + Ahi*Blo (f16 MFMA, f32 acc)
//   A'' [M,512] f16 = [hi|lo]; B'' [N,768] f16 = [Bhi;Bhi;Blo] (k contig per n)
// Shapes fixed: M=Lq=L_in=21760, C=256, NH=8, NL=4, NP=4,
// levels (128,128)(64,64)(32,32)(16,16), lsi {0,16384,20480,21504}
// ---------------------------------------------------------------------------

typedef _Float16 f16;
typedef _Float16 f16x8 __attribute__((ext_vector_type(8)));
typedef _Float16 f16x4 __attribute__((ext_vector_type(4)));
typedef float    f32x4 __attribute__((ext_vector_type(4)));
typedef int      i32x2 __attribute__((ext_vector_type(2)));

__device__ __forceinline__ void g2lds16(const void* gp, void* lp) {
    __builtin_amdgcn_global_load_lds(
        (const __attribute__((address_space(1))) unsigned int*)gp,
        (__attribute__((address_space(3))) unsigned int*)lp, 16, 0, 0);
}

// ---- m97-style split-f16 GEMM core: C[:, coff:coff+128] block at row m0
// A [M,512] f16 (hi|lo), Btb points at this block's 128 B-rows ([*,768] f16)
template <bool HALF_OUT, bool MASKED>
__device__ __forceinline__ void gemm_core(
    const f16* __restrict__ A, const f16* __restrict__ Btb,
    const float* __restrict__ bias,      // per-block, local cols 0..127
    void* __restrict__ C, int ldc, int coff,
    const unsigned char* __restrict__ mask, int m0,
    f16* __restrict__ As, f16* __restrict__ Bs)
{
    const int tid = threadIdx.x, lane = tid & 63, wid = tid >> 6;
    const int wm = (wid >> 1) * 64, wn = (wid & 1) * 64;
    f32x4 acc[4][4] = {};

    const int sr_ = tid >> 2;   // staging row 0..63 (pass adds 64)
    const int sch = tid & 3;    // dest 16B chunk within 64B row

    for (int kt = 0; kt < 24; ++kt) {
        const int kA = (kt < 16 ? kt : kt - 16) * 32;  // kt>=16 revisits hi
        const int kB = kt * 32;
#pragma unroll
        for (int p = 0; p < 2; ++p) {                  // A tile 128x32
            const int r  = p * 64 + sr_;
            const int gc = (sch ^ ((r >> 1) & 3)) << 3;
            g2lds16(A + (size_t)(m0 + r) * 512 + kA + gc, &As[r * 32 + sch * 8]);
        }
#pragma unroll
        for (int p = 0; p < 2; ++p) {                  // B tile 128x32
            const int r  = p * 64 + sr_;
            const int gc = (sch ^ ((r >> 1) & 3)) << 3;
            g2lds16(Btb + (size_t)r * 768 + kB + gc, &Bs[r * 32 + sch * 8]);
        }
        __syncthreads();

        f16x8 av[4], bv[4];
        const int kch = lane >> 4;
#pragma unroll
        for (int mf = 0; mf < 4; ++mf) {
            const int row = wm + mf * 16 + (lane & 15);
            av[mf] = *(const f16x8*)&As[row * 32 + ((kch ^ ((row >> 1) & 3)) << 3)];
        }
#pragma unroll
        for (int nf = 0; nf < 4; ++nf) {
            const int row = wn + nf * 16 + (lane & 15);
            bv[nf] = *(const f16x8*)&Bs[row * 32 + ((kch ^ ((row >> 1) & 3)) << 3)];
        }
#pragma unroll
        for (int mf = 0; mf < 4; ++mf)
#pragma unroll
            for (int nf = 0; nf < 4; ++nf)
                acc[mf][nf] = __builtin_amdgcn_mfma_f32_16x16x32_f16(
                    av[mf], bv[nf], acc[mf][nf], 0, 0, 0);
        __syncthreads();
    }

    // epilogue — C/D layout: col = lane&15, row = (lane>>4)*4 + reg  [m89]
#pragma unroll
    for (int mf = 0; mf < 4; ++mf) {
        const int rb = m0 + wm + mf * 16 + ((lane >> 4) << 2);
#pragma unroll
        for (int nf = 0; nf < 4; ++nf) {
            const int nl = wn + nf * 16 + (lane & 15);
            const float bc = bias[nl];
#pragma unroll
            for (int j = 0; j < 4; ++j) {
                const int row = rb + j;
                float v = acc[mf][nf][j] + bc;
                if (MASKED) v = mask[row] ? 0.f : v;
                if (HALF_OUT)
                    ((__half*)C)[(size_t)row * ldc + coff + nl] = __float2half(v);
                else
                    ((float*)C)[(size_t)row * ldc + coff + nl] = v;
            }
        }
    }
}

// ---- combined GEMM 1: value (blocks 0-1), off->d_out (2-3), logits (4)
__global__ __launch_bounds__(256) void gemm_batch1(
    const f16* __restrict__ A1, const f16* __restrict__ A2,
    const f16* __restrict__ Btv, const f16* __restrict__ Btoa,
    const float* __restrict__ b_v, const float* __restrict__ b_off,
    const float* __restrict__ b_attn,
    __half* __restrict__ valueH, float* __restrict__ outF,
    float* __restrict__ logitF, const unsigned char* __restrict__ mask)
{
    __shared__ __align__(16) f16 As[128 * 32];
    __shared__ __align__(16) f16 Bs[128 * 32];
    const int bx = blockIdx.x, m0 = blockIdx.y * 128;
    if (bx < 2)
        gemm_core<true, true>(A1, Btv + (size_t)bx * 128 * 768, b_v + bx * 128,
                              valueH, 256, bx * 128, mask, m0, As, Bs);
    else if (bx < 4)
        gemm_core<false, false>(A2, Btoa + (size_t)(bx - 2) * 128 * 768,
                                b_off + (bx - 2) * 128, outF, 256,
                                (bx - 2) * 128, nullptr, m0, As, Bs);
    else
        gemm_core<false, false>(A2, Btoa + (size_t)256 * 768, b_attn,
                                logitF, 128, 0, nullptr, m0, As, Bs);
}

// ---- GEMM 2: out = pre @ W_out + b_out
__global__ __launch_bounds__(256) void gemm_batch2(
    const f16* __restrict__ preA, const f16* __restrict__ Btout,
    const float* __restrict__ b_out, float* __restrict__ outF)
{
    __shared__ __align__(16) f16 As[128 * 32];
    __shared__ __align__(16) f16 Bs[128 * 32];
    const int bx = blockIdx.x, m0 = blockIdx.y * 128;
    gemm_core<false, false>(preA, Btout + (size_t)bx * 128 * 768,
                            b_out + bx * 128, outF, 256, bx * 128,
                            nullptr, m0, As, Bs);
}

// ---- fused A-convert: inF -> A1, query -> A2  ([M,256] f32 -> [M,512] hi|lo)
__global__ __launch_bounds__(256) void convA2_kernel(
    const float* __restrict__ inF, const float* __restrict__ query,
    f16* __restrict__ A1, f16* __restrict__ A2, int perT)
{
    const int i = blockIdx.x * 256 + threadIdx.x;
    const float* __restrict__ src = (i < perT) ? inF : query;
    f16* __restrict__ dst = (i < perT) ? A1 : A2;
    const int ii = (i < perT) ? i : i - perT;
    if (ii >= perT) return;
    const int m = ii >> 6, k4 = (ii & 63) << 2;
    const float4 v = reinterpret_cast<const float4*>(src)[ii];
    f16x4 hi, lo;
    hi.x = (f16)v.x; lo.x = (f16)(v.x - (float)hi.x);
    hi.y = (f16)v.y; lo.y = (f16)(v.y - (float)hi.y);
    hi.z = (f16)v.z; lo.z = (f16)(v.z - (float)hi.z);
    hi.w = (f16)v.w; lo.w = (f16)(v.w - (float)hi.w);
    *reinterpret_cast<f16x4*>(&dst[(size_t)m * 512 + k4])       = hi;
    *reinterpret_cast<f16x4*>(&dst[(size_t)m * 512 + 256 + k4]) = lo;
}

// ---- weight prep: Btv | Btoa(off+attn) | Btout
__global__ __launch_bounds__(256) void prep_kernel(
    const float* __restrict__ Wv,   const float* __restrict__ Woff,
    const float* __restrict__ Wattn,const float* __restrict__ Wout,
    f16* __restrict__ Btv, f16* __restrict__ Btoa, f16* __restrict__ Btout)
{
    const int i = blockIdx.x * 256 + threadIdx.x;
    constexpr int S0 = 256 * 768, S1 = 256 * 768, S2 = 128 * 768, S3 = 256 * 768;
    if (i < S0) {
        const int n = i / 768, k = i - n * 768, ks = k & 255;
        const float w = Wv[(size_t)ks * 256 + n];
        const f16 h = (f16)w;
        Btv[i] = (k < 512) ? h : (f16)(w - (float)h);
    } else if (i < S0 + S1) {
        const int j = i - S0;
        const int n = j / 768, k = j - n * 768, ks = k & 255;
        const float w = Woff[(size_t)ks * 256 + n];
        const f16 h = (f16)w;
        Btoa[j] = (k < 512) ? h : (f16)(w - (float)h);
    } else if (i < S0 + S1 + S2) {
        const int j = i - S0 - S1;
        const int n = j / 768, k = j - n * 768, ks = k & 255;
        const float w = Wattn[(size_t)ks * 128 + n];
        const f16 h = (f16)w;
        Btoa[(size_t)(256 + n) * 768 + k] = (k < 512) ? h : (f16)(w - (float)h);
    } else if (i < S0 + S1 + S2 + S3) {
        const int j = i - S0 - S1 - S2;
        const int n = j / 768, k = j - n * 768, ks = k & 255;
        const float w = Wout[(size_t)ks * 256 + n];
        const f16 h = (f16)w;
        Btout[j] = (k < 512) ? h : (f16)(w - (float)h);
    }
}

// ---- sampler v4: 4 queries/block; 4 channels/thread (8B gathers);
//      f32x4 vector FMA; writes preA [M,512] f16 (hi|lo)
__global__ __launch_bounds__(256) void msda_sample_v4(
    const __half* __restrict__ value,    // [L,256] f16
    const float* __restrict__ offF,      // [M,256] f32 (= d_out scratch)
    const float* __restrict__ logitF,    // [M,128] f32
    const float* __restrict__ refp,      // [M,4,2]
    f16* __restrict__ preA)              // [M,512] (hi | lo)
{
    __shared__ float s_off[4][256];
    __shared__ float s_ref[4][8];
    __shared__ __align__(16) float s_w[4][576];   // 8 h-blocks x 72 words
    __shared__ __align__(16) int   s_i[4][576];   // corner-row byte offsets

    const int q0 = blockIdx.x * 4, tid = threadIdx.x;
#pragma unroll
    for (int j = 0; j < 4; ++j) {
        const int idx = tid + j * 256;            // 0..1023
        const int ql = idx >> 8, col = idx & 255;
        s_off[ql][col] = offF[(size_t)(q0 + ql) * 256 + col];
    }
    if (tid < 32) s_ref[tid >> 3][tid & 7] = refp[(size_t)(q0 + (tid >> 3)) * 8 + (tid & 7)];
    __syncthreads();

    // phase 1: (query, head, point) -> softmax + coords + weights
#pragma unroll
    for (int j = 0; j < 2; ++j) {
        const int idx = tid + j * 256;            // 0..511
        const int ql = idx >> 7, slot = idx & 127;
        const int h = slot >> 4, pp = slot & 15, l = pp >> 2, p = pp & 3;
        float v = logitF[(size_t)(q0 + ql) * 128 + slot];
        float mx = v;
#pragma unroll
        for (int o = 1; o < 16; o <<= 1) mx = fmaxf(mx, __shfl_xor(mx, o, 16));
        const float e = expf(v - mx);
        float s = e;
#pragma unroll
        for (int o = 1; o < 16; o <<= 1) s += __shfl_xor(s, o, 16);
        const float a = e / s;

        const int HW_[4]  = {128, 64, 32, 16};
        const int LSI_[4] = {0, 16384, 20480, 21504};
        const int   Wi = HW_[l];
        const float Wf = (float)Wi;
        const float rx = s_ref[ql][l * 2 + 0], ry = s_ref[ql][l * 2 + 1];
        const float ox = s_off[ql][h * 32 + l * 8 + p * 2 + 0];
        const float oy = s_off[ql][h * 32 + l * 8 + p * 2 + 1];
        const float x = (rx + ox / Wf) * Wf - 0.5f;
        const float y = (ry + oy / Wf) * Wf - 0.5f;
        const float x0f = floorf(x), y0f = floorf(y);
        const float dx = x - x0f, dy = y - y0f;
        const int x0 = (int)x0f, y0 = (int)y0f;
        const int x1 = x0 + 1, y1 = y0 + 1;
        const float vx0 = (x0 >= 0 && x0 < Wi) ? 1.f : 0.f;
        const float vx1 = (x1 >= 0 && x1 < Wi) ? 1.f : 0.f;
        const float vy0 = (y0 >= 0 && y0 < Wi) ? 1.f : 0.f;
        const float vy1 = (y1 >= 0 && y1 < Wi) ? 1.f : 0.f;
        const int xc0 = min(max(x0, 0), Wi - 1), xc1 = min(max(x1, 0), Wi - 1);
        const int yc0 = min(max(y0, 0), Wi - 1), yc1 = min(max(y1, 0), Wi - 1);
        const int base = LSI_[l];
        const int eI = h * 72 + pp * 4;
        s_i[ql][eI + 0] = (base + yc0 * Wi + xc0) * 512;
        s_i[ql][eI + 1] = (base + yc0 * Wi + xc1) * 512;
        s_i[ql][eI + 2] = (base + yc1 * Wi + xc0) * 512;
        s_i[ql][eI + 3] = (base + yc1 * Wi + xc1) * 512;
        s_w[ql][eI + 0] = a * (1.f - dy) * (1.f - dx) * vy0 * vx0;
        s_w[ql][eI + 1] = a * (1.f - dy) * dx         * vy0 * vx1;
        s_w[ql][eI + 2] = a * dy         * (1.f - dx) * vy1 * vx0;
        s_w[ql][eI + 3] = a * dy         * dx         * vy1 * vx1;
    }
    __syncthreads();

    // phase 2: thread = (ql, h, 4-channel group); 8B gathers, f32x4 FMA
    const int ql = tid >> 6, slot = tid & 63;
    const int h = slot >> 3, c8 = (slot & 7) << 2;   // channels c8..c8+3
    const int lb = (h * 32 + c8) * 2;                // byte offset within row
    const char* __restrict__ vbase = (const char*)value;
    f32x4 acc = {0.f, 0.f, 0.f, 0.f};
#pragma unroll
    for (int pp = 0; pp < 16; ++pp) {
        const int eI = h * 72 + pp * 4;
        const int4   idx = *reinterpret_cast<const int4*>(&s_i[ql][eI]);
        const float4 wv  = *reinterpret_cast<const float4*>(&s_w[ql][eI]);
        const i32x2 r0 = *reinterpret_cast<const i32x2*>(vbase + (idx.x + lb));
        const i32x2 r1 = *reinterpret_cast<const i32x2*>(vbase + (idx.y + lb));
        const i32x2 r2 = *reinterpret_cast<const i32x2*>(vbase + (idx.z + lb));
        const i32x2 r3 = *reinterpret_cast<const i32x2*>(vbase + (idx.w + lb));
        acc += wv.x * __builtin_convertvector(__builtin_bit_cast(f16x4, r0), f32x4);
        acc += wv.y * __builtin_convertvector(__builtin_bit_cast(f16x4, r1), f32x4);
        acc += wv.z * __builtin_convertvector(__builtin_bit_cast(f16x4, r2), f32x4);
        acc += wv.w * __builtin_convertvector(__builtin_bit_cast(f16x4, r3), f32x4);
    }
    const int q = q0 + ql;
    f16x4 hi, lo;
#pragma unroll
    for (int j = 0; j < 4; ++j) {
        hi[j] = (f16)acc[j];
        lo[j] = (f16)(acc[j] - (float)hi[j]);
    }
    *reinterpret_cast<f16x4*>(&preA[(size_t)q * 512 + h * 32 + c8])       = hi;
    *reinterpret_cast<f16x4*>(&preA[(size_t)q * 512 + 256 + h * 32 + c8]) = lo;
}

extern "C" void kernel_launch(void* const* d_in, const int* in_sizes, int n_in,
                              void* d_out, int out_size, void* d_ws, size_t ws_size,
                              hipStream_t stream)
{
    const float*         query  = (const float*)d_in[0];
    const float*         refp   = (const float*)d_in[1];
    const float*         inF    = (const float*)d_in[2];
    const unsigned char* mask   = (const unsigned char*)d_in[5];
    const float*         W_off  = (const float*)d_in[6];
    const float*         b_off  = (const float*)d_in[7];
    const float*         W_attn = (const float*)d_in[8];
    const float*         b_attn = (const float*)d_in[9];
    const float*         W_v    = (const float*)d_in[10];
    const float*         b_v    = (const float*)d_in[11];
    const float*         W_out  = (const float*)d_in[12];
    const float*         b_out  = (const float*)d_in[13];
    float*               outF   = (float*)d_out;

    const int M = in_sizes[0] / 256;          // 21760
    if (M % 128 != 0) return;                 // tiling guard

    const size_t SZ_A   = (size_t)M * 512 * sizeof(f16);      // 22.3 MB
    const size_t SZ_VAL = (size_t)M * 256 * sizeof(__half);   // 11.1 MB
    const size_t SZ_LG  = (size_t)M * 128 * sizeof(float);    // 11.1 MB
    char* w = (char*)d_ws;
    f16*    A1     = (f16*)w;                      w += SZ_A;   // inF f16 / preA
    f16*    A2     = (f16*)w;                      w += SZ_A;   // query f16
    __half* valueH = (__half*)w;                   w += SZ_VAL;
    float*  logitF = (float*)w;                    w += SZ_LG;
    f16*    Btv    = (f16*)w;                      w += 256 * 768 * sizeof(f16);
    f16*    Btoa   = (f16*)w;                      w += 384 * 768 * sizeof(f16);
    f16*    Btout  = (f16*)w;                      w += 256 * 768 * sizeof(f16);
    if ((size_t)(w - (char*)d_ws) > ws_size) return;  // clean fail, no OOB

    const dim3 blk256(256);
    const int prep_total = (256 + 384 + 256) * 768;
    const int perT = M * 64;

    prep_kernel<<<dim3((prep_total + 255) / 256), blk256, 0, stream>>>(
        W_v, W_off, W_attn, W_out, Btv, Btoa, Btout);

    convA2_kernel<<<dim3((2 * perT + 255) / 256), blk256, 0, stream>>>(
        inF, query, A1, A2, perT);

    // value -> valueH (f16, masked) | off -> d_out (f32) | logits -> logitF
    gemm_batch1<<<dim3(5, M / 128), blk256, 0, stream>>>(
        A1, A2, Btv, Btoa, b_v, b_off, b_attn, valueH, outF, logitF, mask);

    // sampling (+softmax) -> preA (hi|lo) into A1 (inF-A dead now)
    msda_sample_v4<<<dim3(M / 4), blk256, 0, stream>>>(
        valueH, outF, logitF, refp, A1);

    // out = pre @ W_out + b_out  (overwrites all of d_out)
    gemm_batch2<<<dim3(2, M / 128), blk256, 0, stream>>>(A1, Btout, b_out, outF);
}

// Round 10
// 206.333 us; speedup vs baseline: 1.1606x; 1.1606x over previous
//
#include <hip/hip_runtime.h>
#include <hip/hip_bf16.h>
#include <hip/hip_fp16.h>

// ---------------------------------------------------------------------------
// MSDeformableAttention on MI355X — round 10
//  - 2-term split-f16 GEMM (Ahi*Bhi + Alo*Bhi; Blo term dropped, err ~5e-4)
//    BK=64, 8 K-iters, B panel hi-only [N,256] (revisited for lo pass).
//  - value stored [H=8][L][32ch] f16: gather row = 64 contiguous bytes,
//    x0/x1 corners share a 128B line -> L2-friendly.
//  - sampler back to v3 geometry (2 q/block, 128 thr/query, 2ch/thread).
// A'' [M,512] f16 = [hi | lo] (per-row).
// Shapes fixed: M=Lq=L_in=21760, C=256, NH=8, NL=4, NP=4,
// levels (128,128)(64,64)(32,32)(16,16), lsi {0,16384,20480,21504}
// ---------------------------------------------------------------------------

typedef _Float16 f16;
typedef _Float16 f16x8 __attribute__((ext_vector_type(8)));
typedef _Float16 f16x4 __attribute__((ext_vector_type(4)));
typedef _Float16 f16x2 __attribute__((ext_vector_type(2)));
typedef float    f32x4 __attribute__((ext_vector_type(4)));

__device__ __forceinline__ void g2lds16(const void* gp, void* lp) {
    __builtin_amdgcn_global_load_lds(
        (const __attribute__((address_space(1))) unsigned int*)gp,
        (__attribute__((address_space(3))) unsigned int*)lp, 16, 0, 0);
}

// ---- 2-term split-f16 GEMM core: 128x128 tile, 4 waves, 4x4 frags/wave,
// BK=64 (8 iters). A [M,512] f16 (hi|lo), Btb = 128 B-rows of [*,256] f16.
// VLAYOUT: write C as value[h][Ltot][32] f16 (masked).
template <bool VLAYOUT, bool MASKED>
__device__ __forceinline__ void gemm_core(
    const f16* __restrict__ A, const f16* __restrict__ Btb,
    const float* __restrict__ bias,      // per-block, local cols 0..127
    void* __restrict__ C, int ldc, int coff,
    const unsigned char* __restrict__ mask, int m0, int Ltot,
    f16* __restrict__ As, f16* __restrict__ Bs)
{
    const int tid = threadIdx.x, lane = tid & 63, wid = tid >> 6;
    const int wm = (wid >> 1) * 64, wn = (wid & 1) * 64;
    f32x4 acc[4][4] = {};

    const int sr8 = tid >> 3;   // 0..31 (row within 32-row pass group)
    const int sch = tid & 7;    // dest 16B chunk within 128B row

    for (int kt = 0; kt < 8; ++kt) {
        const int kA = kt * 64;            // A f16 cols 0..511 (hi|lo)
        const int kB = (kt & 3) * 64;      // B cols 0..255 (hi panel, revisited)
#pragma unroll
        for (int j = 0; j < 4; ++j) {      // A tile 128x64
            const int r  = j * 32 + sr8;
            const int gc = ((sch ^ (r & 7)) << 3);
            g2lds16(A + (size_t)(m0 + r) * 512 + kA + gc, &As[r * 64 + sch * 8]);
        }
#pragma unroll
        for (int j = 0; j < 4; ++j) {      // B tile 128x64
            const int r  = j * 32 + sr8;
            const int gc = ((sch ^ (r & 7)) << 3);
            g2lds16(Btb + (size_t)r * 256 + kB + gc, &Bs[r * 64 + sch * 8]);
        }
        __syncthreads();

#pragma unroll
        for (int kf = 0; kf < 2; ++kf) {
            const int kch = kf * 4 + (lane >> 4);
            f16x8 av[4], bv[4];
#pragma unroll
            for (int mf = 0; mf < 4; ++mf) {
                const int row = wm + mf * 16 + (lane & 15);
                av[mf] = *(const f16x8*)&As[row * 64 + ((kch ^ (row & 7)) << 3)];
            }
#pragma unroll
            for (int nf = 0; nf < 4; ++nf) {
                const int row = wn + nf * 16 + (lane & 15);
                bv[nf] = *(const f16x8*)&Bs[row * 64 + ((kch ^ (row & 7)) << 3)];
            }
#pragma unroll
            for (int mf = 0; mf < 4; ++mf)
#pragma unroll
                for (int nf = 0; nf < 4; ++nf)
                    acc[mf][nf] = __builtin_amdgcn_mfma_f32_16x16x32_f16(
                        av[mf], bv[nf], acc[mf][nf], 0, 0, 0);
        }
        __syncthreads();
    }

    // epilogue — C/D layout: col = lane&15, row = (lane>>4)*4 + reg  [m89]
#pragma unroll
    for (int mf = 0; mf < 4; ++mf) {
        const int rb = m0 + wm + mf * 16 + ((lane >> 4) << 2);
#pragma unroll
        for (int nf = 0; nf < 4; ++nf) {
            const int nl = wn + nf * 16 + (lane & 15);
            const float bc = bias[nl];
#pragma unroll
            for (int j = 0; j < 4; ++j) {
                const int row = rb + j;
                float v = acc[mf][nf][j] + bc;
                if (MASKED) v = mask[row] ? 0.f : v;
                if (VLAYOUT) {
                    const int col = coff + nl;       // h = col>>5, c = col&31
                    ((__half*)C)[((size_t)(col >> 5) * Ltot + row) * 32 + (col & 31)]
                        = __float2half(v);
                } else {
                    ((float*)C)[(size_t)row * ldc + coff + nl] = v;
                }
            }
        }
    }
}

// ---- combined GEMM 1: value (blocks 0-1), off->d_out (2-3), logits (4)
__global__ __launch_bounds__(256) void gemm_batch1(
    const f16* __restrict__ A1, const f16* __restrict__ A2,
    const f16* __restrict__ Btv, const f16* __restrict__ Btoa,
    const float* __restrict__ b_v, const float* __restrict__ b_off,
    const float* __restrict__ b_attn,
    __half* __restrict__ valueH, float* __restrict__ outF,
    float* __restrict__ logitF, const unsigned char* __restrict__ mask, int M)
{
    __shared__ __align__(16) f16 As[128 * 64];
    __shared__ __align__(16) f16 Bs[128 * 64];
    const int bx = blockIdx.x, m0 = blockIdx.y * 128;
    if (bx < 2)
        gemm_core<true, true>(A1, Btv + (size_t)bx * 128 * 256, b_v + bx * 128,
                              valueH, 0, bx * 128, mask, m0, M, As, Bs);
    else if (bx < 4)
        gemm_core<false, false>(A2, Btoa + (size_t)(bx - 2) * 128 * 256,
                                b_off + (bx - 2) * 128, outF, 256,
                                (bx - 2) * 128, nullptr, m0, M, As, Bs);
    else
        gemm_core<false, false>(A2, Btoa + (size_t)256 * 256, b_attn,
                                logitF, 128, 0, nullptr, m0, M, As, Bs);
}

// ---- GEMM 2: out = pre @ W_out + b_out
__global__ __launch_bounds__(256) void gemm_batch2(
    const f16* __restrict__ preA, const f16* __restrict__ Btout,
    const float* __restrict__ b_out, float* __restrict__ outF, int M)
{
    __shared__ __align__(16) f16 As[128 * 64];
    __shared__ __align__(16) f16 Bs[128 * 64];
    const int bx = blockIdx.x, m0 = blockIdx.y * 128;
    gemm_core<false, false>(preA, Btout + (size_t)bx * 128 * 256,
                            b_out + bx * 128, outF, 256, bx * 128,
                            nullptr, m0, M, As, Bs);
}

// ---- fused A-convert: inF -> A1, query -> A2  ([M,256] f32 -> [M,512] hi|lo)
__global__ __launch_bounds__(256) void convA2_kernel(
    const float* __restrict__ inF, const float* __restrict__ query,
    f16* __restrict__ A1, f16* __restrict__ A2, int perT)
{
    const int i = blockIdx.x * 256 + threadIdx.x;
    const float* __restrict__ src = (i < perT) ? inF : query;
    f16* __restrict__ dst = (i < perT) ? A1 : A2;
    const int ii = (i < perT) ? i : i - perT;
    if (ii >= perT) return;
    const int m = ii >> 6, k4 = (ii & 63) << 2;
    const float4 v = reinterpret_cast<const float4*>(src)[ii];
    f16x4 hi, lo;
    hi.x = (f16)v.x; lo.x = (f16)(v.x - (float)hi.x);
    hi.y = (f16)v.y; lo.y = (f16)(v.y - (float)hi.y);
    hi.z = (f16)v.z; lo.z = (f16)(v.z - (float)hi.z);
    hi.w = (f16)v.w; lo.w = (f16)(v.w - (float)hi.w);
    *reinterpret_cast<f16x4*>(&dst[(size_t)m * 512 + k4])       = hi;
    *reinterpret_cast<f16x4*>(&dst[(size_t)m * 512 + 256 + k4]) = lo;
}

// ---- weight prep (hi-only panels): Bt[n][k] = (f16)W[k][n], [N,256]
__global__ __launch_bounds__(256) void prep_kernel(
    const float* __restrict__ Wv,   const float* __restrict__ Woff,
    const float* __restrict__ Wattn,const float* __restrict__ Wout,
    f16* __restrict__ Btv, f16* __restrict__ Btoa, f16* __restrict__ Btout)
{
    const int i = blockIdx.x * 256 + threadIdx.x;
    constexpr int S0 = 256 * 256, S1 = 256 * 256, S2 = 128 * 256, S3 = 256 * 256;
    if (i < S0) {                                 // W_v -> Btv
        const int n = i >> 8, k = i & 255;
        Btv[i] = (f16)Wv[(size_t)k * 256 + n];
    } else if (i < S0 + S1) {                     // W_off -> Btoa rows 0..255
        const int j = i - S0;
        const int n = j >> 8, k = j & 255;
        Btoa[j] = (f16)Woff[(size_t)k * 256 + n];
    } else if (i < S0 + S1 + S2) {                // W_attn -> Btoa rows 256..383
        const int j = i - S0 - S1;
        const int n = j >> 8, k = j & 255;
        Btoa[(size_t)(256 + n) * 256 + k] = (f16)Wattn[(size_t)k * 128 + n];
    } else if (i < S0 + S1 + S2 + S3) {           // W_out -> Btout
        const int j = i - S0 - S1 - S2;
        const int n = j >> 8, k = j & 255;
        Btout[j] = (f16)Wout[(size_t)k * 256 + n];
    }
}

// ---- sampler v5: v3 geometry (2 q/block, 128 thr/q, 2ch/thread),
//      value [H][Ltot][32] f16 (64B gather rows), stride-72 LDS h-blocks,
//      writes preA [M,512] f16 (hi|lo)
__global__ __launch_bounds__(256) void msda_sample_v5(
    const __half* __restrict__ value,    // [8][Ltot][32] f16
    const float* __restrict__ offF,      // [M,256] f32 (= d_out scratch)
    const float* __restrict__ logitF,    // [M,128] f32
    const float* __restrict__ refp,      // [M,4,2]
    f16* __restrict__ preA, int Ltot)    // [M,512] (hi | lo)
{
    __shared__ float s_off[2][256];
    __shared__ float s_ref[2][8];
    __shared__ __align__(16) float s_w[2][576];   // 8 h-blocks x 72 words
    __shared__ __align__(16) int   s_i[2][576];   // 64B-row byte offsets

    const int q0 = blockIdx.x * 2, tid = threadIdx.x;
#pragma unroll
    for (int j = 0; j < 2; ++j) {
        const int idx = tid + j * 256;
        const int ql = idx >> 8, col = idx & 255;
        s_off[ql][col] = offF[(size_t)(q0 + ql) * 256 + col];
    }
    if (tid < 16) s_ref[tid >> 3][tid & 7] = refp[(size_t)(q0 + (tid >> 3)) * 8 + (tid & 7)];
    __syncthreads();

    // phase 1: thread -> (query, head, point): softmax + coords + weights
    {
        const int ql = tid >> 7, slot = tid & 127;
        const int h = slot >> 4, pp = slot & 15, l = pp >> 2, p = pp & 3;
        float v = logitF[(size_t)(q0 + ql) * 128 + slot];
        float mx = v;
#pragma unroll
        for (int o = 1; o < 16; o <<= 1) mx = fmaxf(mx, __shfl_xor(mx, o, 16));
        const float e = expf(v - mx);
        float s = e;
#pragma unroll
        for (int o = 1; o < 16; o <<= 1) s += __shfl_xor(s, o, 16);
        const float a = e / s;

        const int HW_[4]  = {128, 64, 32, 16};
        const int LSI_[4] = {0, 16384, 20480, 21504};
        const int   Wi = HW_[l];
        const float Wf = (float)Wi;
        const float rx = s_ref[ql][l * 2 + 0], ry = s_ref[ql][l * 2 + 1];
        const float ox = s_off[ql][h * 32 + l * 8 + p * 2 + 0];
        const float oy = s_off[ql][h * 32 + l * 8 + p * 2 + 1];
        const float x = (rx + ox / Wf) * Wf - 0.5f;
        const float y = (ry + oy / Wf) * Wf - 0.5f;
        const float x0f = floorf(x), y0f = floorf(y);
        const float dx = x - x0f, dy = y - y0f;
        const int x0 = (int)x0f, y0 = (int)y0f;
        const int x1 = x0 + 1, y1 = y0 + 1;
        const float vx0 = (x0 >= 0 && x0 < Wi) ? 1.f : 0.f;
        const float vx1 = (x1 >= 0 && x1 < Wi) ? 1.f : 0.f;
        const float vy0 = (y0 >= 0 && y0 < Wi) ? 1.f : 0.f;
        const float vy1 = (y1 >= 0 && y1 < Wi) ? 1.f : 0.f;
        const int xc0 = min(max(x0, 0), Wi - 1), xc1 = min(max(x1, 0), Wi - 1);
        const int yc0 = min(max(y0, 0), Wi - 1), yc1 = min(max(y1, 0), Wi - 1);
        const int hb = h * Ltot + LSI_[l];        // head-slab base row
        const int eI = h * 72 + pp * 4;
        s_i[ql][eI + 0] = (hb + yc0 * Wi + xc0) * 64;
        s_i[ql][eI + 1] = (hb + yc0 * Wi + xc1) * 64;
        s_i[ql][eI + 2] = (hb + yc1 * Wi + xc0) * 64;
        s_i[ql][eI + 3] = (hb + yc1 * Wi + xc1) * 64;
        s_w[ql][eI + 0] = a * (1.f - dy) * (1.f - dx) * vy0 * vx0;
        s_w[ql][eI + 1] = a * (1.f - dy) * dx         * vy0 * vx1;
        s_w[ql][eI + 2] = a * dy         * (1.f - dx) * vy1 * vx0;
        s_w[ql][eI + 3] = a * dy         * dx         * vy1 * vx1;
    }
    __syncthreads();

    // phase 2: thread=(ql, h, cp): 4B half2 gathers + fma_mix accumulate
    const int ql = tid >> 7, slot = tid & 127;
    const int h = slot >> 4, cp = slot & 15;
    const int lb = cp * 4;                         // byte offset within 64B row
    const char* __restrict__ vbase = (const char*)value;
    float acc0 = 0.f, acc1 = 0.f;
#pragma unroll
    for (int pp = 0; pp < 16; ++pp) {
        const int eI = h * 72 + pp * 4;
        const int4   idx = *reinterpret_cast<const int4*>(&s_i[ql][eI]);
        const float4 w   = *reinterpret_cast<const float4*>(&s_w[ql][eI]);
        const __half2 v0 = *reinterpret_cast<const __half2*>(vbase + (idx.x + lb));
        const __half2 v1 = *reinterpret_cast<const __half2*>(vbase + (idx.y + lb));
        const __half2 v2 = *reinterpret_cast<const __half2*>(vbase + (idx.z + lb));
        const __half2 v3 = *reinterpret_cast<const __half2*>(vbase + (idx.w + lb));
        acc0 = fmaf(w.x, __half2float(v0.x), acc0);
        acc1 = fmaf(w.x, __half2float(v0.y), acc1);
        acc0 = fmaf(w.y, __half2float(v1.x), acc0);
        acc1 = fmaf(w.y, __half2float(v1.y), acc1);
        acc0 = fmaf(w.z, __half2float(v2.x), acc0);
        acc1 = fmaf(w.z, __half2float(v2.y), acc1);
        acc0 = fmaf(w.w, __half2float(v3.x), acc0);
        acc1 = fmaf(w.w, __half2float(v3.y), acc1);
    }
    const int q = q0 + ql;
    const f16 h0 = (f16)acc0, h1 = (f16)acc1;
    f16x2 hv; hv.x = h0; hv.y = h1;
    f16x2 lv; lv.x = (f16)(acc0 - (float)h0); lv.y = (f16)(acc1 - (float)h1);
    *reinterpret_cast<f16x2*>(&preA[(size_t)q * 512 + h * 32 + cp * 2])       = hv;
    *reinterpret_cast<f16x2*>(&preA[(size_t)q * 512 + 256 + h * 32 + cp * 2]) = lv;
}

extern "C" void kernel_launch(void* const* d_in, const int* in_sizes, int n_in,
                              void* d_out, int out_size, void* d_ws, size_t ws_size,
                              hipStream_t stream)
{
    const float*         query  = (const float*)d_in[0];
    const float*         refp   = (const float*)d_in[1];
    const float*         inF    = (const float*)d_in[2];
    const unsigned char* mask   = (const unsigned char*)d_in[5];
    const float*         W_off  = (const float*)d_in[6];
    const float*         b_off  = (const float*)d_in[7];
    const float*         W_attn = (const float*)d_in[8];
    const float*         b_attn = (const float*)d_in[9];
    const float*         W_v    = (const float*)d_in[10];
    const float*         b_v    = (const float*)d_in[11];
    const float*         W_out  = (const float*)d_in[12];
    const float*         b_out  = (const float*)d_in[13];
    float*               outF   = (float*)d_out;

    const int M = in_sizes[0] / 256;          // 21760
    if (M % 128 != 0) return;                 // tiling guard

    const size_t SZ_A   = (size_t)M * 512 * sizeof(f16);      // 22.3 MB
    const size_t SZ_VAL = (size_t)M * 256 * sizeof(__half);   // 11.1 MB
    const size_t SZ_LG  = (size_t)M * 128 * sizeof(float);    // 11.1 MB
    char* w = (char*)d_ws;
    f16*    A1     = (f16*)w;                      w += SZ_A;   // inF f16 / preA
    f16*    A2     = (f16*)w;                      w += SZ_A;   // query f16
    __half* valueH = (__half*)w;                   w += SZ_VAL; // [8][M][32]
    float*  logitF = (float*)w;                    w += SZ_LG;
    f16*    Btv    = (f16*)w;                      w += 256 * 256 * sizeof(f16);
    f16*    Btoa   = (f16*)w;                      w += 384 * 256 * sizeof(f16);
    f16*    Btout  = (f16*)w;                      w += 256 * 256 * sizeof(f16);
    if ((size_t)(w - (char*)d_ws) > ws_size) return;  // clean fail, no OOB

    const dim3 blk256(256);
    const int prep_total = (256 + 384 + 256) * 256;
    const int perT = M * 64;

    prep_kernel<<<dim3((prep_total + 255) / 256), blk256, 0, stream>>>(
        W_v, W_off, W_attn, W_out, Btv, Btoa, Btout);

    convA2_kernel<<<dim3((2 * perT + 255) / 256), blk256, 0, stream>>>(
        inF, query, A1, A2, perT);

    // value -> valueH ([H][M][32] f16, masked) | off -> d_out | logits -> logitF
    gemm_batch1<<<dim3(5, M / 128), blk256, 0, stream>>>(
        A1, A2, Btv, Btoa, b_v, b_off, b_attn, valueH, outF, logitF, mask, M);

    // sampling (+softmax) -> preA (hi|lo) into A1 (inF-A dead now)
    msda_sample_v5<<<dim3(M / 2), blk256, 0, stream>>>(
        valueH, outF, logitF, refp, A1, M);

    // out = pre @ W_out + b_out  (overwrites all of d_out)
    gemm_batch2<<<dim3(2, M / 128), blk256, 0, stream>>>(A1, Btout, b_out, outF, M);
}

// Round 12
// 203.846 us; speedup vs baseline: 1.1747x; 1.0122x over previous
//
#include <hip/hip_runtime.h>
#include <hip/hip_bf16.h>
#include <hip/hip_fp16.h>

// ---------------------------------------------------------------------------
// MSDeformableAttention on MI355X — round 12 (= round 11; r11 bench was an
// infra acquisition timeout, kernel never executed)
//  r10 + ONE change: gemm_core pipelined (T3 minimum 2-phase recipe):
//  double-buffered LDS, next-tile global_load_lds issued BEFORE compute,
//  ONE barrier per K-iter (its implicit vmcnt(0) waits on loads that had the
//  whole MFMA+ds_read phase to land). Was: 2 barriers/iter, staging latency
//  fully exposed. Everything else identical to the passing round-10 kernel.
//  - 2-term split-f16 GEMM (Ahi*Bhi + Alo*Bhi), BK=64, 8 K-iters.
//  - value stored [H=8][L][32ch] f16 (64B gather rows).
//  - sampler v5 (2 q/block, 128 thr/query, 2ch/thread).
// Shapes fixed: M=Lq=L_in=21760, C=256, NH=8, NL=4, NP=4,
// levels (128,128)(64,64)(32,32)(16,16), lsi {0,16384,20480,21504}
// ---------------------------------------------------------------------------

typedef _Float16 f16;
typedef _Float16 f16x8 __attribute__((ext_vector_type(8)));
typedef _Float16 f16x4 __attribute__((ext_vector_type(4)));
typedef _Float16 f16x2 __attribute__((ext_vector_type(2)));
typedef float    f32x4 __attribute__((ext_vector_type(4)));

__device__ __forceinline__ void g2lds16(const void* gp, void* lp) {
    __builtin_amdgcn_global_load_lds(
        (const __attribute__((address_space(1))) unsigned int*)gp,
        (__attribute__((address_space(3))) unsigned int*)lp, 16, 0, 0);
}

// ---- 2-term split-f16 GEMM core, PIPELINED: 128x128 tile, 4 waves,
// 4x4 frags/wave, BK=64 (8 iters), double-buffered LDS (As/Bs: [2][128*64]).
// A [M,512] f16 (hi|lo), Btb = 128 B-rows of [*,256] f16.
// VLAYOUT: write C as value[h][Ltot][32] f16 (masked).
template <bool VLAYOUT, bool MASKED>
__device__ __forceinline__ void gemm_core(
    const f16* __restrict__ A, const f16* __restrict__ Btb,
    const float* __restrict__ bias,      // per-block, local cols 0..127
    void* __restrict__ C, int ldc, int coff,
    const unsigned char* __restrict__ mask, int m0, int Ltot,
    f16* __restrict__ As, f16* __restrict__ Bs)   // each [2][128*64] flat
{
    const int tid = threadIdx.x, lane = tid & 63, wid = tid >> 6;
    const int wm = (wid >> 1) * 64, wn = (wid & 1) * 64;
    f32x4 acc[4][4] = {};

    const int sr8 = tid >> 3;   // 0..31 (row within 32-row pass group)
    const int sch = tid & 7;    // dest 16B chunk within 128B row

    // stage K-tile kt into buffer buf (8 g2lds16/thread, linear-lane dest)
    auto stage = [&](int buf, int kt) {
        const int kA = kt * 64;            // A f16 cols (hi|lo span 0..511)
        const int kB = (kt & 3) * 64;      // B hi panel 0..255, revisited
        f16* __restrict__ Ab = As + buf * (128 * 64);
        f16* __restrict__ Bb = Bs + buf * (128 * 64);
#pragma unroll
        for (int j = 0; j < 4; ++j) {
            const int r  = j * 32 + sr8;
            const int gc = ((sch ^ (r & 7)) << 3);
            g2lds16(A + (size_t)(m0 + r) * 512 + kA + gc, &Ab[r * 64 + sch * 8]);
        }
#pragma unroll
        for (int j = 0; j < 4; ++j) {
            const int r  = j * 32 + sr8;
            const int gc = ((sch ^ (r & 7)) << 3);
            g2lds16(Btb + (size_t)r * 256 + kB + gc, &Bb[r * 64 + sch * 8]);
        }
    };

    stage(0, 0);
    __syncthreads();                      // tile 0 ready (vmcnt(0) drain)

    for (int kt = 0; kt < 8; ++kt) {
        const int cur = kt & 1;
        if (kt < 7) stage(cur ^ 1, kt + 1);   // issue next tile FIRST (async)

        const f16* __restrict__ Ab = As + cur * (128 * 64);
        const f16* __restrict__ Bb = Bs + cur * (128 * 64);
#pragma unroll
        for (int kf = 0; kf < 2; ++kf) {
            const int kch = kf * 4 + (lane >> 4);
            f16x8 av[4], bv[4];
#pragma unroll
            for (int mf = 0; mf < 4; ++mf) {
                const int row = wm + mf * 16 + (lane & 15);
                av[mf] = *(const f16x8*)&Ab[row * 64 + ((kch ^ (row & 7)) << 3)];
            }
#pragma unroll
            for (int nf = 0; nf < 4; ++nf) {
                const int row = wn + nf * 16 + (lane & 15);
                bv[nf] = *(const f16x8*)&Bb[row * 64 + ((kch ^ (row & 7)) << 3)];
            }
#pragma unroll
            for (int mf = 0; mf < 4; ++mf)
#pragma unroll
                for (int nf = 0; nf < 4; ++nf)
                    acc[mf][nf] = __builtin_amdgcn_mfma_f32_16x16x32_f16(
                        av[mf], bv[nf], acc[mf][nf], 0, 0, 0);
        }
        __syncthreads();   // drains this iter's stage (landed under compute)
                           // + my ds_reads; next iter may overwrite buf[cur]
    }

    // epilogue — C/D layout: col = lane&15, row = (lane>>4)*4 + reg  [m89]
#pragma unroll
    for (int mf = 0; mf < 4; ++mf) {
        const int rb = m0 + wm + mf * 16 + ((lane >> 4) << 2);
#pragma unroll
        for (int nf = 0; nf < 4; ++nf) {
            const int nl = wn + nf * 16 + (lane & 15);
            const float bc = bias[nl];
#pragma unroll
            for (int j = 0; j < 4; ++j) {
                const int row = rb + j;
                float v = acc[mf][nf][j] + bc;
                if (MASKED) v = mask[row] ? 0.f : v;
                if (VLAYOUT) {
                    const int col = coff + nl;       // h = col>>5, c = col&31
                    ((__half*)C)[((size_t)(col >> 5) * Ltot + row) * 32 + (col & 31)]
                        = __float2half(v);
                } else {
                    ((float*)C)[(size_t)row * ldc + coff + nl] = v;
                }
            }
        }
    }
}

// ---- combined GEMM 1: value (blocks 0-1), off->d_out (2-3), logits (4)
__global__ __launch_bounds__(256) void gemm_batch1(
    const f16* __restrict__ A1, const f16* __restrict__ A2,
    const f16* __restrict__ Btv, const f16* __restrict__ Btoa,
    const float* __restrict__ b_v, const float* __restrict__ b_off,
    const float* __restrict__ b_attn,
    __half* __restrict__ valueH, float* __restrict__ outF,
    float* __restrict__ logitF, const unsigned char* __restrict__ mask, int M)
{
    __shared__ __align__(16) f16 As[2][128 * 64];
    __shared__ __align__(16) f16 Bs[2][128 * 64];
    const int bx = blockIdx.x, m0 = blockIdx.y * 128;
    if (bx < 2)
        gemm_core<true, true>(A1, Btv + (size_t)bx * 128 * 256, b_v + bx * 128,
                              valueH, 0, bx * 128, mask, m0, M, &As[0][0], &Bs[0][0]);
    else if (bx < 4)
        gemm_core<false, false>(A2, Btoa + (size_t)(bx - 2) * 128 * 256,
                                b_off + (bx - 2) * 128, outF, 256,
                                (bx - 2) * 128, nullptr, m0, M, &As[0][0], &Bs[0][0]);
    else
        gemm_core<false, false>(A2, Btoa + (size_t)256 * 256, b_attn,
                                logitF, 128, 0, nullptr, m0, M, &As[0][0], &Bs[0][0]);
}

// ---- GEMM 2: out = pre @ W_out + b_out
__global__ __launch_bounds__(256) void gemm_batch2(
    const f16* __restrict__ preA, const f16* __restrict__ Btout,
    const float* __restrict__ b_out, float* __restrict__ outF, int M)
{
    __shared__ __align__(16) f16 As[2][128 * 64];
    __shared__ __align__(16) f16 Bs[2][128 * 64];
    const int bx = blockIdx.x, m0 = blockIdx.y * 128;
    gemm_core<false, false>(preA, Btout + (size_t)bx * 128 * 256,
                            b_out + bx * 128, outF, 256, bx * 128,
                            nullptr, m0, M, &As[0][0], &Bs[0][0]);
}

// ---- fused A-convert: inF -> A1, query -> A2  ([M,256] f32 -> [M,512] hi|lo)
__global__ __launch_bounds__(256) void convA2_kernel(
    const float* __restrict__ inF, const float* __restrict__ query,
    f16* __restrict__ A1, f16* __restrict__ A2, int perT)
{
    const int i = blockIdx.x * 256 + threadIdx.x;
    const float* __restrict__ src = (i < perT) ? inF : query;
    f16* __restrict__ dst = (i < perT) ? A1 : A2;
    const int ii = (i < perT) ? i : i - perT;
    if (ii >= perT) return;
    const int m = ii >> 6, k4 = (ii & 63) << 2;
    const float4 v = reinterpret_cast<const float4*>(src)[ii];
    f16x4 hi, lo;
    hi.x = (f16)v.x; lo.x = (f16)(v.x - (float)hi.x);
    hi.y = (f16)v.y; lo.y = (f16)(v.y - (float)hi.y);
    hi.z = (f16)v.z; lo.z = (f16)(v.z - (float)hi.z);
    hi.w = (f16)v.w; lo.w = (f16)(v.w - (float)hi.w);
    *reinterpret_cast<f16x4*>(&dst[(size_t)m * 512 + k4])       = hi;
    *reinterpret_cast<f16x4*>(&dst[(size_t)m * 512 + 256 + k4]) = lo;
}

// ---- weight prep (hi-only panels): Bt[n][k] = (f16)W[k][n], [N,256]
__global__ __launch_bounds__(256) void prep_kernel(
    const float* __restrict__ Wv,   const float* __restrict__ Woff,
    const float* __restrict__ Wattn,const float* __restrict__ Wout,
    f16* __restrict__ Btv, f16* __restrict__ Btoa, f16* __restrict__ Btout)
{
    const int i = blockIdx.x * 256 + threadIdx.x;
    constexpr int S0 = 256 * 256, S1 = 256 * 256, S2 = 128 * 256, S3 = 256 * 256;
    if (i < S0) {                                 // W_v -> Btv
        const int n = i >> 8, k = i & 255;
        Btv[i] = (f16)Wv[(size_t)k * 256 + n];
    } else if (i < S0 + S1) {                     // W_off -> Btoa rows 0..255
        const int j = i - S0;
        const int n = j >> 8, k = j & 255;
        Btoa[j] = (f16)Woff[(size_t)k * 256 + n];
    } else if (i < S0 + S1 + S2) {                // W_attn -> Btoa rows 256..383
        const int j = i - S0 - S1;
        const int n = j >> 8, k = j & 255;
        Btoa[(size_t)(256 + n) * 256 + k] = (f16)Wattn[(size_t)k * 128 + n];
    } else if (i < S0 + S1 + S2 + S3) {           // W_out -> Btout
        const int j = i - S0 - S1 - S2;
        const int n = j >> 8, k = j & 255;
        Btout[j] = (f16)Wout[(size_t)k * 256 + n];
    }
}

// ---- sampler v5: 2 q/block, 128 thr/q, 2ch/thread; value [H][Ltot][32] f16,
//      stride-72 LDS h-blocks; writes preA [M,512] f16 (hi|lo)
__global__ __launch_bounds__(256) void msda_sample_v5(
    const __half* __restrict__ value,    // [8][Ltot][32] f16
    const float* __restrict__ offF,      // [M,256] f32 (= d_out scratch)
    const float* __restrict__ logitF,    // [M,128] f32
    const float* __restrict__ refp,      // [M,4,2]
    f16* __restrict__ preA, int Ltot)    // [M,512] (hi | lo)
{
    __shared__ float s_off[2][256];
    __shared__ float s_ref[2][8];
    __shared__ __align__(16) float s_w[2][576];   // 8 h-blocks x 72 words
    __shared__ __align__(16) int   s_i[2][576];   // 64B-row byte offsets

    const int q0 = blockIdx.x * 2, tid = threadIdx.x;
#pragma unroll
    for (int j = 0; j < 2; ++j) {
        const int idx = tid + j * 256;
        const int ql = idx >> 8, col = idx & 255;
        s_off[ql][col] = offF[(size_t)(q0 + ql) * 256 + col];
    }
    if (tid < 16) s_ref[tid >> 3][tid & 7] = refp[(size_t)(q0 + (tid >> 3)) * 8 + (tid & 7)];
    __syncthreads();

    // phase 1: thread -> (query, head, point): softmax + coords + weights
    {
        const int ql = tid >> 7, slot = tid & 127;
        const int h = slot >> 4, pp = slot & 15, l = pp >> 2, p = pp & 3;
        float v = logitF[(size_t)(q0 + ql) * 128 + slot];
        float mx = v;
#pragma unroll
        for (int o = 1; o < 16; o <<= 1) mx = fmaxf(mx, __shfl_xor(mx, o, 16));
        const float e = expf(v - mx);
        float s = e;
#pragma unroll
        for (int o = 1; o < 16; o <<= 1) s += __shfl_xor(s, o, 16);
        const float a = e / s;

        const int HW_[4]  = {128, 64, 32, 16};
        const int LSI_[4] = {0, 16384, 20480, 21504};
        const int   Wi = HW_[l];
        const float Wf = (float)Wi;
        const float rx = s_ref[ql][l * 2 + 0], ry = s_ref[ql][l * 2 + 1];
        const float ox = s_off[ql][h * 32 + l * 8 + p * 2 + 0];
        const float oy = s_off[ql][h * 32 + l * 8 + p * 2 + 1];
        const float x = (rx + ox / Wf) * Wf - 0.5f;
        const float y = (ry + oy / Wf) * Wf - 0.5f;
        const float x0f = floorf(x), y0f = floorf(y);
        const float dx = x - x0f, dy = y - y0f;
        const int x0 = (int)x0f, y0 = (int)y0f;
        const int x1 = x0 + 1, y1 = y0 + 1;
        const float vx0 = (x0 >= 0 && x0 < Wi) ? 1.f : 0.f;
        const float vx1 = (x1 >= 0 && x1 < Wi) ? 1.f : 0.f;
        const float vy0 = (y0 >= 0 && y0 < Wi) ? 1.f : 0.f;
        const float vy1 = (y1 >= 0 && y1 < Wi) ? 1.f : 0.f;
        const int xc0 = min(max(x0, 0), Wi - 1), xc1 = min(max(x1, 0), Wi - 1);
        const int yc0 = min(max(y0, 0), Wi - 1), yc1 = min(max(y1, 0), Wi - 1);
        const int hb = h * Ltot + LSI_[l];        // head-slab base row
        const int eI = h * 72 + pp * 4;
        s_i[ql][eI + 0] = (hb + yc0 * Wi + xc0) * 64;
        s_i[ql][eI + 1] = (hb + yc0 * Wi + xc1) * 64;
        s_i[ql][eI + 2] = (hb + yc1 * Wi + xc0) * 64;
        s_i[ql][eI + 3] = (hb + yc1 * Wi + xc1) * 64;
        s_w[ql][eI + 0] = a * (1.f - dy) * (1.f - dx) * vy0 * vx0;
        s_w[ql][eI + 1] = a * (1.f - dy) * dx         * vy0 * vx1;
        s_w[ql][eI + 2] = a * dy         * (1.f - dx) * vy1 * vx0;
        s_w[ql][eI + 3] = a * dy         * dx         * vy1 * vx1;
    }
    __syncthreads();

    // phase 2: thread=(ql, h, cp): 4B half2 gathers + mixed FMA accumulate
    const int ql = tid >> 7, slot = tid & 127;
    const int h = slot >> 4, cp = slot & 15;
    const int lb = cp * 4;                         // byte offset within 64B row
    const char* __restrict__ vbase = (const char*)value;
    float acc0 = 0.f, acc1 = 0.f;
#pragma unroll
    for (int pp = 0; pp < 16; ++pp) {
        const int eI = h * 72 + pp * 4;
        const int4   idx = *reinterpret_cast<const int4*>(&s_i[ql][eI]);
        const float4 w   = *reinterpret_cast<const float4*>(&s_w[ql][eI]);
        const __half2 v0 = *reinterpret_cast<const __half2*>(vbase + (idx.x + lb));
        const __half2 v1 = *reinterpret_cast<const __half2*>(vbase + (idx.y + lb));
        const __half2 v2 = *reinterpret_cast<const __half2*>(vbase + (idx.z + lb));
        const __half2 v3 = *reinterpret_cast<const __half2*>(vbase + (idx.w + lb));
        acc0 = fmaf(w.x, __half2float(v0.x), acc0);
        acc1 = fmaf(w.x, __half2float(v0.y), acc1);
        acc0 = fmaf(w.y, __half2float(v1.x), acc0);
        acc1 = fmaf(w.y, __half2float(v1.y), acc1);
        acc0 = fmaf(w.z, __half2float(v2.x), acc0);
        acc1 = fmaf(w.z, __half2float(v2.y), acc1);
        acc0 = fmaf(w.w, __half2float(v3.x), acc0);
        acc1 = fmaf(w.w, __half2float(v3.y), acc1);
    }
    const int q = q0 + ql;
    const f16 h0 = (f16)acc0, h1 = (f16)acc1;
    f16x2 hv; hv.x = h0; hv.y = h1;
    f16x2 lv; lv.x = (f16)(acc0 - (float)h0); lv.y = (f16)(acc1 - (float)h1);
    *reinterpret_cast<f16x2*>(&preA[(size_t)q * 512 + h * 32 + cp * 2])       = hv;
    *reinterpret_cast<f16x2*>(&preA[(size_t)q * 512 + 256 + h * 32 + cp * 2]) = lv;
}

extern "C" void kernel_launch(void* const* d_in, const int* in_sizes, int n_in,
                              void* d_out, int out_size, void* d_ws, size_t ws_size,
                              hipStream_t stream)
{
    const float*         query  = (const float*)d_in[0];
    const float*         refp   = (const float*)d_in[1];
    const float*         inF    = (const float*)d_in[2];
    const unsigned char* mask   = (const unsigned char*)d_in[5];
    const float*         W_off  = (const float*)d_in[6];
    const float*         b_off  = (const float*)d_in[7];
    const float*         W_attn = (const float*)d_in[8];
    const float*         b_attn = (const float*)d_in[9];
    const float*         W_v    = (const float*)d_in[10];
    const float*         b_v    = (const float*)d_in[11];
    const float*         W_out  = (const float*)d_in[12];
    const float*         b_out  = (const float*)d_in[13];
    float*               outF   = (float*)d_out;

    const int M = in_sizes[0] / 256;          // 21760
    if (M % 128 != 0) return;                 // tiling guard

    const size_t SZ_A   = (size_t)M * 512 * sizeof(f16);      // 22.3 MB
    const size_t SZ_VAL = (size_t)M * 256 * sizeof(__half);   // 11.1 MB
    const size_t SZ_LG  = (size_t)M * 128 * sizeof(float);    // 11.1 MB
    char* w = (char*)d_ws;
    f16*    A1     = (f16*)w;                      w += SZ_A;   // inF f16 / preA
    f16*    A2     = (f16*)w;                      w += SZ_A;   // query f16
    __half* valueH = (__half*)w;                   w += SZ_VAL; // [8][M][32]
    float*  logitF = (float*)w;                    w += SZ_LG;
    f16*    Btv    = (f16*)w;                      w += 256 * 256 * sizeof(f16);
    f16*    Btoa   = (f16*)w;                      w += 384 * 256 * sizeof(f16);
    f16*    Btout  = (f16*)w;                      w += 256 * 256 * sizeof(f16);
    if ((size_t)(w - (char*)d_ws) > ws_size) return;  // clean fail, no OOB

    const dim3 blk256(256);
    const int prep_total = (256 + 384 + 256) * 256;
    const int perT = M * 64;

    prep_kernel<<<dim3((prep_total + 255) / 256), blk256, 0, stream>>>(
        W_v, W_off, W_attn, W_out, Btv, Btoa, Btout);

    convA2_kernel<<<dim3((2 * perT + 255) / 256), blk256, 0, stream>>>(
        inF, query, A1, A2, perT);

    // value -> valueH ([H][M][32] f16, masked) | off -> d_out | logits -> logitF
    gemm_batch1<<<dim3(5, M / 128), blk256, 0, stream>>>(
        A1, A2, Btv, Btoa, b_v, b_off, b_attn, valueH, outF, logitF, mask, M);

    // sampling (+softmax) -> preA (hi|lo) into A1 (inF-A dead now)
    msda_sample_v5<<<dim3(M / 2), blk256, 0, stream>>>(
        valueH, outF, logitF, refp, A1, M);

    // out = pre @ W_out + b_out  (overwrites all of d_out)
    gemm_batch2<<<dim3(2, M / 128), blk256, 0, stream>>>(A1, Btout, b_out, outF, M);
}